// Round 6
// baseline (124.771 us; speedup 1.0000x reference)
//
#include <hip/hip_runtime.h>
#include <hip/hip_bf16.h>

// MaxPoolingMatching: out[b,l,p] = max_m cos( s1[b,l,:]∘k[p,:], s2[b,m,:]∘k[p,:] )
// B=16, L=256, D=256, P=20.
//
// v6: SINGLE fused kernel (the 2-dispatch graph-node overhead was the residual).
// Block (b, lt, pgi) self-contained:
//   phase 0: areg = bf16(s2) MFMA-A-fragments loaded straight from fp32 global;
//            s1 tile cached as packed bf16; X1 buffer temporarily holds bf16(s1)²;
//            KQ = bf16(k²) (5 p rows) in LDS.
//   norms:   m-side: MFMA with A = squared areg frags (in-register), B = KQ -> RN2.
//            l-side: MFMA with A = s1² frags from X1, B = KQ -> RN1. All in LDS.
//   p-loop (5): build X1 = bf16(s1·k²·rn1) (swizzled), K-loop 2 ds_read_b128 +
//            8 MFMA per kstep (A from VGPRs), epilogue ×rn2, max over m in-lane +
//            shfl_xor(16,32), cross-wave via Wout. No workspace, no second kernel.

#define B_DIM 16
#define L_DIM 256
#define D_DIM 256
#define P_DIM 20
#define EPS 1e-12f

typedef __attribute__((ext_vector_type(8))) __bf16 bf16x8;
typedef __attribute__((ext_vector_type(4))) float f32x4;

union frag_cast { uint4 u; bf16x8 v; };

__device__ __forceinline__ unsigned short f2bf(float x) {
  unsigned int u = __float_as_uint(x);
  u += 0x7fffu + ((u >> 16) & 1u);   // RNE
  return (unsigned short)(u >> 16);
}

__device__ __forceinline__ unsigned int sq2(unsigned int w) {
  // squares of two packed bf16 -> packed bf16
  float lo = __uint_as_float(w << 16);
  float hi = __uint_as_float(w & 0xffff0000u);
  return (unsigned int)f2bf(lo * lo) | ((unsigned int)f2bf(hi * hi) << 16);
}

__device__ __forceinline__ bf16x8 square_frag(bf16x8 a) {
  frag_cast in, out;
  in.v = a;
  out.u.x = sq2(in.u.x); out.u.y = sq2(in.u.y);
  out.u.z = sq2(in.u.z); out.u.w = sq2(in.u.w);
  return out.v;
}

__global__ __launch_bounds__(256, 2)
void mpm_fused(const float* __restrict__ s1, const float* __restrict__ s2,
               const float* __restrict__ kg, float* __restrict__ outg) {
  __shared__ __align__(16) unsigned short X1[32 * 256];  // 16KB: s1² (phase0), X1 (p-loop)
  __shared__ __align__(16) unsigned short KQ[5 * 264];   // bf16(k²) rows, padded
  __shared__ __align__(16) float RN2[5][260];            // rsqrt norms, m-side
  __shared__ float RN1[5][32];                           // rsqrt norms, l-side
  __shared__ float Wout[128];

  const int tid = threadIdx.x, lane = tid & 63, wave = tid >> 6;  // 4 waves
  const int lr = lane & 15, q = lane >> 4;
  const int bid = blockIdx.x;      // 512 = b(16) x lt(8) x pgi(4)
  const int pgi = bid & 3, lt = (bid >> 2) & 7, b = bid >> 5;
  const int l0 = lt * 32;

  // ---- areg: wave's 64 m-rows as A-fragments, from fp32 global ----
  // lane holds row m = wave*64 + mi*16 + lr, d = ks*32 + q*8 + {0..7}
  bf16x8 areg[4][8];
  {
    const float* s2b = s2 + (size_t)b * L_DIM * D_DIM;
    #pragma unroll
    for (int mi = 0; mi < 4; ++mi) {
      const float* rp = s2b + (size_t)(wave * 64 + mi * 16 + lr) * D_DIM + q * 8;
      #pragma unroll
      for (int ks = 0; ks < 8; ++ks) {
        float4 u = *(const float4*)(rp + ks * 32);
        float4 w = *(const float4*)(rp + ks * 32 + 4);
        frag_cast f;
        f.u.x = (unsigned int)f2bf(u.x) | ((unsigned int)f2bf(u.y) << 16);
        f.u.y = (unsigned int)f2bf(u.z) | ((unsigned int)f2bf(u.w) << 16);
        f.u.z = (unsigned int)f2bf(w.x) | ((unsigned int)f2bf(w.y) << 16);
        f.u.w = (unsigned int)f2bf(w.z) | ((unsigned int)f2bf(w.w) << 16);
        areg[mi][ks] = f.v;
      }
    }
  }

  // ---- s1 tile: 8 rows/wave packed bf16; also write bf16(s1)² into X1 (swizzled) ----
  uint2 s1r[8];
  {
    const float* s1b = s1 + ((size_t)b * L_DIM + l0) * D_DIM;
    #pragma unroll
    for (int i = 0; i < 8; ++i) {
      const int row = i * 4 + wave;
      float4 sv = *(const float4*)(s1b + (size_t)row * D_DIM + lane * 4);
      uint2 pk;
      pk.x = (unsigned int)f2bf(sv.x) | ((unsigned int)f2bf(sv.y) << 16);
      pk.y = (unsigned int)f2bf(sv.z) | ((unsigned int)f2bf(sv.w) << 16);
      s1r[i] = pk;
      uint2 sq = make_uint2(sq2(pk.x), sq2(pk.y));
      *(uint2*)&X1[row * 256 + (((lane >> 1) ^ row) << 3) + ((lane & 1) << 2)] = sq;
    }
  }

  // ---- KQ = bf16(k²) for this block's 5 p's ----
  for (int r = wave; r < 5; r += 4) {
    float4 kv = *(const float4*)(kg + (size_t)(pgi * 5 + r) * D_DIM + lane * 4);
    uint2 pk;
    pk.x = (unsigned int)f2bf(kv.x * kv.x) | ((unsigned int)f2bf(kv.y * kv.y) << 16);
    pk.y = (unsigned int)f2bf(kv.z * kv.z) | ((unsigned int)f2bf(kv.w * kv.w) << 16);
    *(uint2*)&KQ[r * 264 + lane * 4] = pk;
  }
  __syncthreads();   // X1(=s1²), KQ visible

  // ---- norms via MFMA: C[row=m_tile(q*4+r), col=p(lr)] ----
  // m-side: A = squared areg frags (in-register)
  #pragma unroll
  for (int mi = 0; mi < 4; ++mi) {
    f32x4 nacc = {0.f, 0.f, 0.f, 0.f};
    #pragma unroll
    for (int ks = 0; ks < 8; ++ks) {
      bf16x8 asq = square_frag(areg[mi][ks]);
      bf16x8 bq = *(const bf16x8*)&KQ[lr * 264 + (ks * 4 + q) * 8];
      nacc = __builtin_amdgcn_mfma_f32_16x16x32_bf16(asq, bq, nacc, 0, 0, 0);
    }
    if (lr < 5) {
      #pragma unroll
      for (int r = 0; r < 4; ++r)
        RN2[lr][wave * 64 + mi * 16 + q * 4 + r] = rsqrtf(fmaxf(nacc[r], EPS));
    }
  }
  // l-side: A = s1² frags from X1 (waves 0,1 handle the two 16-row tiles)
  if (wave < 2) {
    const int ti = wave, row = ti * 16 + lr;
    f32x4 nacc = {0.f, 0.f, 0.f, 0.f};
    #pragma unroll
    for (int ks = 0; ks < 8; ++ks) {
      const int cc = ks * 4 + q;
      bf16x8 asq = *(const bf16x8*)&X1[row * 256 + ((cc ^ row) << 3)];
      bf16x8 bq  = *(const bf16x8*)&KQ[lr * 264 + cc * 8];
      nacc = __builtin_amdgcn_mfma_f32_16x16x32_bf16(asq, bq, nacc, 0, 0, 0);
    }
    if (lr < 5) {
      #pragma unroll
      for (int r = 0; r < 4; ++r)
        RN1[lr][ti * 16 + q * 4 + r] = rsqrtf(fmaxf(nacc[r], EPS));
    }
  }
  __syncthreads();   // RN1/RN2 visible; X1-as-s1² reads done

  // ---- p-loop ----
  #pragma unroll 1
  for (int pp = 0; pp < 5; ++pp) {
    const int p = pgi * 5 + pp;

    // build X1 = bf16( s1 * k² * rn1 ), swizzled
    {
      float4 kv = *(const float4*)(kg + (size_t)p * D_DIM + lane * 4);
      const float k0 = kv.x * kv.x, k1 = kv.y * kv.y, k2 = kv.z * kv.z, k3 = kv.w * kv.w;
      #pragma unroll
      for (int i = 0; i < 8; ++i) {
        const int row = i * 4 + wave;
        const float rv = RN1[pp][row];
        float x0 = __uint_as_float(s1r[i].x << 16)         * k0 * rv;
        float x1 = __uint_as_float(s1r[i].x & 0xffff0000u) * k1 * rv;
        float x2 = __uint_as_float(s1r[i].y << 16)         * k2 * rv;
        float x3 = __uint_as_float(s1r[i].y & 0xffff0000u) * k3 * rv;
        unsigned int c0 = ((unsigned int)f2bf(x1) << 16) | f2bf(x0);
        unsigned int c1 = ((unsigned int)f2bf(x3) << 16) | f2bf(x2);
        *(uint2*)&X1[row * 256 + (((lane >> 1) ^ row) << 3) + ((lane & 1) << 2)] =
            make_uint2(c0, c1);
      }
    }
    __syncthreads();   // X1 visible

    // K-loop: wave computes C[64m x 32l]; A from VGPRs, B from LDS
    f32x4 acc[4][2];
    #pragma unroll
    for (int mi = 0; mi < 4; ++mi) {
      acc[mi][0] = (f32x4){0.f, 0.f, 0.f, 0.f};
      acc[mi][1] = (f32x4){0.f, 0.f, 0.f, 0.f};
    }
    #pragma unroll
    for (int ks = 0; ks < 8; ++ks) {
      const int cc = ks * 4 + q;
      bf16x8 b0 = *(const bf16x8*)&X1[(lr)      * 256 + ((cc ^ lr) << 3)];
      bf16x8 b1 = *(const bf16x8*)&X1[(16 + lr) * 256 + ((cc ^ (16 + lr)) << 3)];
      #pragma unroll
      for (int mi = 0; mi < 4; ++mi) {
        acc[mi][0] = __builtin_amdgcn_mfma_f32_16x16x32_bf16(areg[mi][ks], b0, acc[mi][0], 0, 0, 0);
        acc[mi][1] = __builtin_amdgcn_mfma_f32_16x16x32_bf16(areg[mi][ks], b1, acc[mi][1], 0, 0, 0);
      }
    }

    // epilogue: C row = m = wave*64 + mi*16 + q*4 + r ; col l = li*16 + lr
    float4 r2[4];
    #pragma unroll
    for (int mi = 0; mi < 4; ++mi)
      r2[mi] = *(const float4*)&RN2[pp][wave * 64 + mi * 16 + q * 4];
    float v[2];
    #pragma unroll
    for (int li = 0; li < 2; ++li) {
      float t = -3.4e38f;
      #pragma unroll
      for (int mi = 0; mi < 4; ++mi) {
        t = fmaxf(t, acc[mi][li][0] * r2[mi].x);
        t = fmaxf(t, acc[mi][li][1] * r2[mi].y);
        t = fmaxf(t, acc[mi][li][2] * r2[mi].z);
        t = fmaxf(t, acc[mi][li][3] * r2[mi].w);
      }
      t = fmaxf(t, __shfl_xor(t, 16));
      t = fmaxf(t, __shfl_xor(t, 32));
      v[li] = t;
    }
    if (q == 0) {
      Wout[wave * 32 + lr]      = v[0];
      Wout[wave * 32 + 16 + lr] = v[1];
    }
    __syncthreads();   // Wout visible; X1 reads done
    if (tid < 32) {
      float o = fmaxf(fmaxf(Wout[tid], Wout[32 + tid]),
                      fmaxf(Wout[64 + tid], Wout[96 + tid]));
      outg[((size_t)b * L_DIM + (l0 + tid)) * P_DIM + p] = o;
    }
  }
}

extern "C" void kernel_launch(void* const* d_in, const int* in_sizes, int n_in,
                              void* d_out, int out_size, void* d_ws, size_t ws_size,
                              hipStream_t stream) {
  const float* s1 = (const float*)d_in[0];
  const float* s2 = (const float*)d_in[1];
  const float* kg = (const float*)d_in[2];
  float* out = (float*)d_out;
  mpm_fused<<<dim3(512), dim3(256), 0, stream>>>(s1, s2, kg, out);
}